// Round 8
// baseline (212.696 us; speedup 1.0000x reference)
//
#include <hip/hip_runtime.h>
#include <hip/hip_bf16.h>

#define NHALF 4096
#define TWO_N 8192
#define DDIM 256
#define INV_T 10.0f
// 10 * log2(e): exp(10*s) = exp2(s * SCALE) where s is the raw cosine dot
#define SCALE 14.426950408889634f

typedef __bf16 v8bf __attribute__((ext_vector_type(8)));
typedef float f32x4 __attribute__((ext_vector_type(4)));

#if __has_builtin(__builtin_amdgcn_exp2f)
#define EXP2F(x) __builtin_amdgcn_exp2f(x)
#else
#define EXP2F(x) exp2f(x)
#endif

static __device__ __forceinline__ unsigned short f2bf(float x) {
    __hip_bfloat16 h = __float2bfloat16(x);
    return *(unsigned short*)&h;
}

// ---------------- kernel 1: normalize rows -> bf16 zn; zero rowacc & out ----
__global__ __launch_bounds__(256) void ntx_norm_kernel(
    const float* __restrict__ zi, const float* __restrict__ zj,
    __hip_bfloat16* __restrict__ zn, float* __restrict__ rowacc,
    float* __restrict__ out) {
    const int w = threadIdx.x >> 6;
    const int lane = threadIdx.x & 63;
    const int r = blockIdx.x * 4 + w;
    const float* src = (r < NHALF) ? (zi + (size_t)r * DDIM)
                                   : (zj + (size_t)(r - NHALF) * DDIM);
    float4 v = ((const float4*)src)[lane];
    float ss = v.x * v.x + v.y * v.y + v.z * v.z + v.w * v.w;
#pragma unroll
    for (int m = 1; m < 64; m <<= 1) ss += __shfl_xor(ss, m);
    float rinv = 1.0f / fmaxf(sqrtf(ss), 1e-8f);
    ushort4 o;
    o.x = f2bf(v.x * rinv);
    o.y = f2bf(v.y * rinv);
    o.z = f2bf(v.z * rinv);
    o.w = f2bf(v.w * rinv);
    ((ushort4*)(zn + (size_t)r * DDIM))[lane] = o;
    if (blockIdx.x < 32) rowacc[blockIdx.x * 256 + threadIdx.x] = 0.0f;
    if (blockIdx.x == 0 && threadIdx.x == 0) out[0] = 0.0f;
}

// ---------------- kernel 2: symmetric Gram + exp sums ----------------
// 64 row-groups of 128; blocks enumerate pairs (I >= J): 2080 blocks
// (~8.1/CU -> tail ~11%; R7 failure: 528 blocks = 2.06/CU, 30% tail +
// 2 waves/SIMD latency exposure). Block = S[I:128][J:128], K=256 in one pass.
// 4 waves; wave owns 32 rows: af[2][8]=64 VGPRs pinned. J-cols streamed in
// 4 chunks of 32 via a SINGLE 16.5 KB LDS buffer (8 blocks/CU by LDS);
// next-chunk loads issue right after ds_write -> land during compute (T14).
// Row-sums -> rowacc[I rows]; col-sums (mirror, by symmetry) -> rowacc[J rows].
// Positives on local diag of I-J==32 blocks; diag masked in I==J blocks.
__global__ __launch_bounds__(256, 8) void ntx_gram_kernel(
    const __hip_bfloat16* __restrict__ zn,
    float* __restrict__ rowacc,    // [TWO_N] atomic accumulation
    float* __restrict__ spos) {    // [TWO_N]
    // triangle decode over 64 groups
    const int b = blockIdx.x;
    int I = (int)((sqrtf(8.0f * b + 1.0f) - 1.0f) * 0.5f);
    while ((I + 1) * (I + 2) / 2 <= b) ++I;
    while (I * (I + 1) / 2 > b) --I;
    const int J = b - I * (I + 1) / 2;
    const bool sameIJ = (I == J);
    const bool posblk = (I - J) == 32;
    const int Ibase = I * 128, Jbase = J * 128;

    const int tid = threadIdx.x;
    const int w = tid >> 6;
    const int lane = tid & 63;
    const int lrow = lane & 15;        // A-row / B-col / C-col within 16-tile
    const int lk = lane >> 4;          // k-group 0..3
    const int wr = w * 32;             // wave's local row base

    const char* znb = (const char*)zn; // row stride = 512 B

    __shared__ f32x4 ldsv[1024 + 32];  // 16 KB chunk buf + 512 B scol
    char* lds = (char*)ldsv;
    float* scol = (float*)(lds + 16384);
    if (tid < 128) scol[tid] = 0.0f;   // col-sum accumulator (128 cols)

    // A fragments: zn[Ibase + wr + rf*16 + lrow][kb*32 + lk*8 .. +7]
    f32x4 af[2][8];
#pragma unroll
    for (int rf = 0; rf < 2; ++rf) {
        const char* abase =
            znb + (((size_t)(Ibase + wr + rf * 16 + lrow)) << 9) + (lk << 4);
#pragma unroll
        for (int kb = 0; kb < 8; ++kb)
            af[rf][kb] = *(const f32x4*)(abase + kb * 64);
    }
#pragma unroll
    for (int rf = 0; rf < 2; ++rf)
#pragma unroll
        for (int kb = 0; kb < 8; ++kb)
            asm volatile("" : "+v"(af[rf][kb]));  // pin: no remat/sink

    bool ondiag[4];
#pragma unroll
    for (int j = 0; j < 4; ++j) ondiag[j] = (lrow == lk * 4 + j);
    const int rdxor = lrow & 7;

    // staging map: 16KB chunk = 32 J-rows x 32 slots(16B); thread piece p:
    // row=(tid>>5)+p*8, slot=tid&31; write swizzle slot^(row&7).
    const int srow = tid >> 5, sslot = tid & 31;
    int wroff[4];
#pragma unroll
    for (int p = 0; p < 4; ++p) {
        const int rr = srow + p * 8;
        wroff[p] = rr * 512 + ((sslot ^ (rr & 7)) << 4);
    }

    float rowsum[2][4];
#pragma unroll
    for (int rf = 0; rf < 2; ++rf)
#pragma unroll
        for (int j = 0; j < 4; ++j) rowsum[rf][j] = 0.0f;

#define LOADST(st, cc)                                                        \
    do {                                                                      \
        const char* tb = znb + (((size_t)(Jbase + (cc) * 32)) << 9);          \
        _Pragma("unroll")                                                     \
        for (int p = 0; p < 4; ++p)                                           \
            st[p] = *(const f32x4*)(tb + tid * 16 + p * 4096);                \
    } while (0)

#define WRITEST(st)                                                           \
    do {                                                                      \
        _Pragma("unroll")                                                     \
        for (int p = 0; p < 4; ++p) *(f32x4*)(lds + wroff[p]) = st[p];        \
    } while (0)

#define COMPUTE(cc)                                                           \
    do {                                                                      \
        f32x4 acc[2][2];                                                      \
        _Pragma("unroll")                                                     \
        for (int rf = 0; rf < 2; ++rf)                                        \
            _Pragma("unroll")                                                 \
            for (int cf = 0; cf < 2; ++cf)                                    \
                acc[rf][cf] = (f32x4){0.f, 0.f, 0.f, 0.f};                    \
        _Pragma("unroll")                                                     \
        for (int kb = 0; kb < 8; ++kb) {                                      \
            f32x4 bf[2];                                                      \
            _Pragma("unroll")                                                 \
            for (int cf = 0; cf < 2; ++cf)                                    \
                bf[cf] = *(const f32x4*)(lds + (cf * 16 + lrow) * 512 +       \
                                         (((lk + 4 * kb) ^ rdxor) << 4));     \
            _Pragma("unroll")                                                 \
            for (int rf = 0; rf < 2; ++rf)                                    \
                _Pragma("unroll")                                             \
                for (int cf = 0; cf < 2; ++cf)                                \
                    acc[rf][cf] = __builtin_amdgcn_mfma_f32_16x16x32_bf16(    \
                        __builtin_bit_cast(v8bf, af[rf][kb]),                 \
                        __builtin_bit_cast(v8bf, bf[cf]), acc[rf][cf],        \
                        0, 0, 0);                                             \
        }                                                                     \
        float ce0 = 0.0f, ce1 = 0.0f;                                         \
        _Pragma("unroll")                                                     \
        for (int rf = 0; rf < 2; ++rf) {                                      \
            const int rurow = wr + rf * 16;                                   \
            _Pragma("unroll")                                                 \
            for (int cf = 0; cf < 2; ++cf) {                                  \
                const bool dm = (rurow == (cc) * 32 + cf * 16);               \
                _Pragma("unroll")                                             \
                for (int j = 0; j < 4; ++j) {                                 \
                    const float s = acc[rf][cf][j];                           \
                    const bool od = dm && ondiag[j];                          \
                    if (posblk && od) {                                       \
                        const int u = rurow + lk * 4 + j;                     \
                        spos[Ibase + u] = s * INV_T;                          \
                        spos[Jbase + u] = s * INV_T;                          \
                    }                                                         \
                    const float e = EXP2F(s * SCALE);                         \
                    rowsum[rf][j] += (sameIJ && od) ? 0.0f : e;               \
                    if (cf == 0) ce0 += e; else ce1 += e;                     \
                }                                                             \
            }                                                                 \
        }                                                                     \
        if (!sameIJ) {                                                        \
            ce0 += __shfl_xor(ce0, 16); ce0 += __shfl_xor(ce0, 32);           \
            ce1 += __shfl_xor(ce1, 16); ce1 += __shfl_xor(ce1, 32);           \
            if (lane < 16) {                                                  \
                atomicAdd(&scol[(cc) * 32 + lrow], ce0);                      \
                atomicAdd(&scol[(cc) * 32 + 16 + lrow], ce1);                 \
            }                                                                 \
        }                                                                     \
    } while (0)

    f32x4 stA[4], stB[4];
    LOADST(stA, 0);
    // ch 0
    WRITEST(stA);
    LOADST(stB, 1);
    __syncthreads();
    COMPUTE(0);
    __syncthreads();
    // ch 1
    WRITEST(stB);
    LOADST(stA, 2);
    __syncthreads();
    COMPUTE(1);
    __syncthreads();
    // ch 2
    WRITEST(stA);
    LOADST(stB, 3);
    __syncthreads();
    COMPUTE(2);
    __syncthreads();
    // ch 3
    WRITEST(stB);
    __syncthreads();
    COMPUTE(3);
#undef LOADST
#undef WRITEST
#undef COMPUTE

    // flush row-sums (reduce over the 16 col-lanes)
#pragma unroll
    for (int rf = 0; rf < 2; ++rf) {
#pragma unroll
        for (int j = 0; j < 4; ++j) {
            float v = rowsum[rf][j];
            v += __shfl_xor(v, 1);
            v += __shfl_xor(v, 2);
            v += __shfl_xor(v, 4);
            v += __shfl_xor(v, 8);
            if (lrow == 0)
                atomicAdd(&rowacc[Ibase + wr + rf * 16 + lk * 4 + j], v);
        }
    }
    // flush col-sums (mirror contribution) for off-diagonal blocks
    __syncthreads();
    if (!sameIJ && tid < 128) atomicAdd(&rowacc[Jbase + tid], scol[tid]);
}

// ---------------- kernel 3: finalize ----------------
__global__ __launch_bounds__(256) void ntx_final_kernel(
    const float* __restrict__ rowacc, const float* __restrict__ spos,
    float* __restrict__ out) {
    const int tid = threadIdx.x;
    const int r = blockIdx.x * 256 + tid;
    float nll = logf(rowacc[r]) - spos[r];
    __shared__ float red[256];
    red[tid] = nll;
    __syncthreads();
    for (int s = 128; s > 0; s >>= 1) {
        if (tid < s) red[tid] += red[tid + s];
        __syncthreads();
    }
    if (tid == 0) atomicAdd(out, red[0] * (1.0f / (float)TWO_N));
}

extern "C" void kernel_launch(void* const* d_in, const int* in_sizes, int n_in,
                              void* d_out, int out_size, void* d_ws, size_t ws_size,
                              hipStream_t stream) {
    const float* zi = (const float*)d_in[0];
    const float* zj = (const float*)d_in[1];
    char* ws = (char*)d_ws;
    __hip_bfloat16* zn = (__hip_bfloat16*)ws;                          // 4 MB
    size_t off = (size_t)TWO_N * DDIM * 2;
    float* spos = (float*)(ws + off);                                  // 32 KB
    off += (size_t)TWO_N * 4;
    float* rowacc = (float*)(ws + off);                                // 32 KB
    float* out = (float*)d_out;

    ntx_norm_kernel<<<TWO_N / 4, 256, 0, stream>>>(zi, zj, zn, rowacc, out);
    ntx_gram_kernel<<<2080, 256, 0, stream>>>(zn, rowacc, spos);
    ntx_final_kernel<<<TWO_N / 256, 256, 0, stream>>>(rowacc, spos, out);
}

// Round 9
// 57.876 us; speedup vs baseline: 3.6751x; 3.6751x over previous
//
#include <hip/hip_runtime.h>
#include <hip/hip_bf16.h>

#define NHALF 4096
#define TWO_N 8192
#define DDIM 256
#define INV_T 10.0f
// 10 * log2(e): exp(10*s) = exp2(s * SCALE) where s is the raw cosine dot
#define SCALE 14.426950408889634f

typedef __bf16 v8bf __attribute__((ext_vector_type(8)));
typedef float f32x4 __attribute__((ext_vector_type(4)));

#if __has_builtin(__builtin_amdgcn_exp2f)
#define EXP2F(x) __builtin_amdgcn_exp2f(x)
#else
#define EXP2F(x) exp2f(x)
#endif

static __device__ __forceinline__ unsigned short f2bf(float x) {
    __hip_bfloat16 h = __float2bfloat16(x);
    return *(unsigned short*)&h;
}

// ---------------- kernel 1: normalize rows -> bf16 zn; zero rowacc & out ----
__global__ __launch_bounds__(256) void ntx_norm_kernel(
    const float* __restrict__ zi, const float* __restrict__ zj,
    __hip_bfloat16* __restrict__ zn, float* __restrict__ rowacc,
    float* __restrict__ out) {
    const int w = threadIdx.x >> 6;
    const int lane = threadIdx.x & 63;
    const int r = blockIdx.x * 4 + w;
    const float* src = (r < NHALF) ? (zi + (size_t)r * DDIM)
                                   : (zj + (size_t)(r - NHALF) * DDIM);
    float4 v = ((const float4*)src)[lane];
    float ss = v.x * v.x + v.y * v.y + v.z * v.z + v.w * v.w;
#pragma unroll
    for (int m = 1; m < 64; m <<= 1) ss += __shfl_xor(ss, m);
    float rinv = 1.0f / fmaxf(sqrtf(ss), 1e-8f);
    ushort4 o;
    o.x = f2bf(v.x * rinv);
    o.y = f2bf(v.y * rinv);
    o.z = f2bf(v.z * rinv);
    o.w = f2bf(v.w * rinv);
    ((ushort4*)(zn + (size_t)r * DDIM))[lane] = o;
    if (blockIdx.x < 32) rowacc[blockIdx.x * 256 + threadIdx.x] = 0.0f;
    if (blockIdx.x == 0 && threadIdx.x == 0) out[0] = 0.0f;
}

// ---------------- kernel 2: symmetric Gram + exp sums ----------------
// 64 row-groups of 128; blocks enumerate pairs (I >= J): 2080 blocks.
// Block = S[I:128][J:128], K=256 in one pass. 4 waves; wave owns 32 rows:
// af[2][8]=64 VGPRs pinned. J-cols streamed in 4 chunks of 32 via a single
// 16.5 KB LDS buffer; next-chunk loads issue right after ds_write (T14).
// __launch_bounds__(256,3): VGPR budget ~168 >= demand ~140. (R8 failure:
// (256,8) -> 32-VGPR budget -> total spill, 780 MB scratch traffic, 220 us.)
// Row-sums -> rowacc[I rows]; col-sums (mirror, by symmetry) -> rowacc[J rows].
// Positives on local diag of I-J==32 blocks; diag masked in I==J blocks.
__global__ __launch_bounds__(256, 3) void ntx_gram_kernel(
    const __hip_bfloat16* __restrict__ zn,
    float* __restrict__ rowacc,    // [TWO_N] atomic accumulation
    float* __restrict__ spos) {    // [TWO_N]
    // triangle decode over 64 groups
    const int b = blockIdx.x;
    int I = (int)((sqrtf(8.0f * b + 1.0f) - 1.0f) * 0.5f);
    while ((I + 1) * (I + 2) / 2 <= b) ++I;
    while (I * (I + 1) / 2 > b) --I;
    const int J = b - I * (I + 1) / 2;
    const bool sameIJ = (I == J);
    const bool posblk = (I - J) == 32;
    const int Ibase = I * 128, Jbase = J * 128;

    const int tid = threadIdx.x;
    const int w = tid >> 6;
    const int lane = tid & 63;
    const int lrow = lane & 15;        // A-row / B-col / C-col within 16-tile
    const int lk = lane >> 4;          // k-group 0..3
    const int wr = w * 32;             // wave's local row base

    const char* znb = (const char*)zn; // row stride = 512 B

    __shared__ f32x4 ldsv[1024 + 32];  // 16 KB chunk buf + 512 B scol
    char* lds = (char*)ldsv;
    float* scol = (float*)(lds + 16384);
    if (tid < 128) scol[tid] = 0.0f;   // col-sum accumulator (128 cols)

    // A fragments: zn[Ibase + wr + rf*16 + lrow][kb*32 + lk*8 .. +7]
    f32x4 af[2][8];
#pragma unroll
    for (int rf = 0; rf < 2; ++rf) {
        const char* abase =
            znb + (((size_t)(Ibase + wr + rf * 16 + lrow)) << 9) + (lk << 4);
#pragma unroll
        for (int kb = 0; kb < 8; ++kb)
            af[rf][kb] = *(const f32x4*)(abase + kb * 64);
    }
#pragma unroll
    for (int rf = 0; rf < 2; ++rf)
#pragma unroll
        for (int kb = 0; kb < 8; ++kb)
            asm volatile("" : "+v"(af[rf][kb]));  // pin: no remat/sink

    bool ondiag[4];
#pragma unroll
    for (int j = 0; j < 4; ++j) ondiag[j] = (lrow == lk * 4 + j);
    const int rdxor = lrow & 7;

    // staging map: 16KB chunk = 32 J-rows x 32 slots(16B); thread piece p:
    // row=(tid>>5)+p*8, slot=tid&31; write swizzle slot^(row&7).
    const int srow = tid >> 5, sslot = tid & 31;
    int wroff[4];
#pragma unroll
    for (int p = 0; p < 4; ++p) {
        const int rr = srow + p * 8;
        wroff[p] = rr * 512 + ((sslot ^ (rr & 7)) << 4);
    }

    float rowsum[2][4];
#pragma unroll
    for (int rf = 0; rf < 2; ++rf)
#pragma unroll
        for (int j = 0; j < 4; ++j) rowsum[rf][j] = 0.0f;

#define LOADST(st, cc)                                                        \
    do {                                                                      \
        const char* tb = znb + (((size_t)(Jbase + (cc) * 32)) << 9);          \
        _Pragma("unroll")                                                     \
        for (int p = 0; p < 4; ++p)                                           \
            st[p] = *(const f32x4*)(tb + tid * 16 + p * 4096);                \
    } while (0)

#define WRITEST(st)                                                           \
    do {                                                                      \
        _Pragma("unroll")                                                     \
        for (int p = 0; p < 4; ++p) *(f32x4*)(lds + wroff[p]) = st[p];        \
    } while (0)

#define COMPUTE(cc)                                                           \
    do {                                                                      \
        f32x4 acc[2][2];                                                      \
        _Pragma("unroll")                                                     \
        for (int rf = 0; rf < 2; ++rf)                                        \
            _Pragma("unroll")                                                 \
            for (int cf = 0; cf < 2; ++cf)                                    \
                acc[rf][cf] = (f32x4){0.f, 0.f, 0.f, 0.f};                    \
        _Pragma("unroll")                                                     \
        for (int kb = 0; kb < 8; ++kb) {                                      \
            f32x4 bf[2];                                                      \
            _Pragma("unroll")                                                 \
            for (int cf = 0; cf < 2; ++cf)                                    \
                bf[cf] = *(const f32x4*)(lds + (cf * 16 + lrow) * 512 +       \
                                         (((lk + 4 * kb) ^ rdxor) << 4));     \
            _Pragma("unroll")                                                 \
            for (int rf = 0; rf < 2; ++rf)                                    \
                _Pragma("unroll")                                             \
                for (int cf = 0; cf < 2; ++cf)                                \
                    acc[rf][cf] = __builtin_amdgcn_mfma_f32_16x16x32_bf16(    \
                        __builtin_bit_cast(v8bf, af[rf][kb]),                 \
                        __builtin_bit_cast(v8bf, bf[cf]), acc[rf][cf],        \
                        0, 0, 0);                                             \
        }                                                                     \
        float ce0 = 0.0f, ce1 = 0.0f;                                         \
        _Pragma("unroll")                                                     \
        for (int rf = 0; rf < 2; ++rf) {                                      \
            const int rurow = wr + rf * 16;                                   \
            _Pragma("unroll")                                                 \
            for (int cf = 0; cf < 2; ++cf) {                                  \
                const bool dm = (rurow == (cc) * 32 + cf * 16);               \
                _Pragma("unroll")                                             \
                for (int j = 0; j < 4; ++j) {                                 \
                    const float s = acc[rf][cf][j];                           \
                    const bool od = dm && ondiag[j];                          \
                    if (posblk && od) {                                       \
                        const int u = rurow + lk * 4 + j;                     \
                        spos[Ibase + u] = s * INV_T;                          \
                        spos[Jbase + u] = s * INV_T;                          \
                    }                                                         \
                    const float e = EXP2F(s * SCALE);                         \
                    rowsum[rf][j] += (sameIJ && od) ? 0.0f : e;               \
                    if (cf == 0) ce0 += e; else ce1 += e;                     \
                }                                                             \
            }                                                                 \
        }                                                                     \
        if (!sameIJ) {                                                        \
            ce0 += __shfl_xor(ce0, 16); ce0 += __shfl_xor(ce0, 32);           \
            ce1 += __shfl_xor(ce1, 16); ce1 += __shfl_xor(ce1, 32);           \
            if (lane < 16) {                                                  \
                atomicAdd(&scol[(cc) * 32 + lrow], ce0);                      \
                atomicAdd(&scol[(cc) * 32 + 16 + lrow], ce1);                 \
            }                                                                 \
        }                                                                     \
    } while (0)

    f32x4 stA[4], stB[4];
    LOADST(stA, 0);
    // ch 0
    WRITEST(stA);
    LOADST(stB, 1);
    __syncthreads();
    COMPUTE(0);
    __syncthreads();
    // ch 1
    WRITEST(stB);
    LOADST(stA, 2);
    __syncthreads();
    COMPUTE(1);
    __syncthreads();
    // ch 2
    WRITEST(stA);
    LOADST(stB, 3);
    __syncthreads();
    COMPUTE(2);
    __syncthreads();
    // ch 3
    WRITEST(stB);
    __syncthreads();
    COMPUTE(3);
#undef LOADST
#undef WRITEST
#undef COMPUTE

    // flush row-sums (reduce over the 16 col-lanes)
#pragma unroll
    for (int rf = 0; rf < 2; ++rf) {
#pragma unroll
        for (int j = 0; j < 4; ++j) {
            float v = rowsum[rf][j];
            v += __shfl_xor(v, 1);
            v += __shfl_xor(v, 2);
            v += __shfl_xor(v, 4);
            v += __shfl_xor(v, 8);
            if (lrow == 0)
                atomicAdd(&rowacc[Ibase + wr + rf * 16 + lk * 4 + j], v);
        }
    }
    // flush col-sums (mirror contribution) for off-diagonal blocks
    __syncthreads();
    if (!sameIJ && tid < 128) atomicAdd(&rowacc[Jbase + tid], scol[tid]);
}

// ---------------- kernel 3: finalize ----------------
__global__ __launch_bounds__(256) void ntx_final_kernel(
    const float* __restrict__ rowacc, const float* __restrict__ spos,
    float* __restrict__ out) {
    const int tid = threadIdx.x;
    const int r = blockIdx.x * 256 + tid;
    float nll = logf(rowacc[r]) - spos[r];
    __shared__ float red[256];
    red[tid] = nll;
    __syncthreads();
    for (int s = 128; s > 0; s >>= 1) {
        if (tid < s) red[tid] += red[tid + s];
        __syncthreads();
    }
    if (tid == 0) atomicAdd(out, red[0] * (1.0f / (float)TWO_N));
}

extern "C" void kernel_launch(void* const* d_in, const int* in_sizes, int n_in,
                              void* d_out, int out_size, void* d_ws, size_t ws_size,
                              hipStream_t stream) {
    const float* zi = (const float*)d_in[0];
    const float* zj = (const float*)d_in[1];
    char* ws = (char*)d_ws;
    __hip_bfloat16* zn = (__hip_bfloat16*)ws;                          // 4 MB
    size_t off = (size_t)TWO_N * DDIM * 2;
    float* spos = (float*)(ws + off);                                  // 32 KB
    off += (size_t)TWO_N * 4;
    float* rowacc = (float*)(ws + off);                                // 32 KB
    float* out = (float*)d_out;

    ntx_norm_kernel<<<TWO_N / 4, 256, 0, stream>>>(zi, zj, zn, rowacc, out);
    ntx_gram_kernel<<<2080, 256, 0, stream>>>(zn, rowacc, spos);
    ntx_final_kernel<<<TWO_N / 256, 256, 0, stream>>>(rowacc, spos, out);
}